// Round 7
// baseline (368.743 us; speedup 1.0000x reference)
//
#include <hip/hip_runtime.h>
#include <math.h>

#define TPB 256
#define SCAN_T 256
#define SCAN_I 4
#define SCAN_CHUNK 1024  // SCAN_T * SCAN_I

typedef __attribute__((ext_vector_type(8))) short bf16x8;
typedef __attribute__((ext_vector_type(16))) float f32x16;

static __device__ __forceinline__ short f2bf(float a) {
  unsigned ua = __builtin_bit_cast(unsigned, a);
  ua = (ua + 0x7fffu + ((ua >> 16) & 1u)) >> 16;
  return (short)ua;
}
static __device__ __forceinline__ unsigned f2bf_pack(float a, float b) {
  unsigned ua = __builtin_bit_cast(unsigned, a);
  unsigned ub = __builtin_bit_cast(unsigned, b);
  ua = (ua + 0x7fffu + ((ua >> 16) & 1u)) >> 16;
  ub = (ub + 0x7fffu + ((ub >> 16) & 1u)) >> 16;
  return ua | (ub << 16);
}
static __device__ __forceinline__ float bflo(unsigned u) {
  return __builtin_bit_cast(float, u << 16);
}
static __device__ __forceinline__ float bfhi(unsigned u) {
  return __builtin_bit_cast(float, u & 0xffff0000u);
}

// ---------------- CSR build ----------------
__global__ void k_zero_int(int* __restrict__ p, int n) {
  int t = blockIdx.x * TPB + threadIdx.x;
  if (t < n) p[t] = 0;
}

__global__ void k_hist(const int* __restrict__ dst, int* __restrict__ deg, int E) {
  int t = blockIdx.x * TPB + threadIdx.x;
  if (t < E) atomicAdd(&deg[dst[t]], 1);
}

__global__ __launch_bounds__(SCAN_T) void k_scan_local(const int* __restrict__ deg,
                                                       int* __restrict__ loc,
                                                       int* __restrict__ bsum, int N) {
  __shared__ int s[SCAN_T];
  int b = blockIdx.x, t = threadIdx.x;
  int base = b * SCAN_CHUNK + t * SCAN_I;
  int v[SCAN_I];
  int sum = 0;
#pragma unroll
  for (int u = 0; u < SCAN_I; u++) {
    int x = (base + u < N) ? deg[base + u] : 0;
    v[u] = sum;
    sum += x;
  }
  s[t] = sum;
  __syncthreads();
#pragma unroll
  for (int off = 1; off < SCAN_T; off <<= 1) {
    int x = (t >= off) ? s[t - off] : 0;
    __syncthreads();
    s[t] += x;
    __syncthreads();
  }
  int excl = (t == 0) ? 0 : s[t - 1];
#pragma unroll
  for (int u = 0; u < SCAN_I; u++)
    if (base + u < N) loc[base + u] = v[u] + excl;
  if (t == SCAN_T - 1) bsum[b] = s[t];
}

__global__ void k_scan_block(int* __restrict__ bsum, int nb) {
  if (threadIdx.x == 0 && blockIdx.x == 0) {
    int run = 0;
    for (int i = 0; i < nb; i++) {
      int tmp = bsum[i];
      bsum[i] = run;
      run += tmp;
    }
  }
}

__global__ void k_scan_add(int* __restrict__ rowoff, const int* __restrict__ bsum,
                           int* __restrict__ cursor, const int* __restrict__ deg,
                           float* __restrict__ dinv, int N) {
  int t = blockIdx.x * TPB + threadIdx.x;
  if (t >= N) return;
  int ro = rowoff[t] + bsum[t / SCAN_CHUNK];
  rowoff[t] = ro;
  cursor[t] = ro;
  dinv[t] = rsqrtf((float)deg[t] + 1.0f);
}

// slots[pos]=src, eids[pos]=edge id, dpos[pos]=dst  (dst-sorted position order)
__global__ void k_fill_slots(const int* __restrict__ src, const int* __restrict__ dst,
                             int* __restrict__ cursor, int* __restrict__ slots,
                             int* __restrict__ eids, int* __restrict__ dpos, int E) {
  int e = blockIdx.x * TPB + threadIdx.x;
  if (e >= E) return;
  int d = dst[e];
  int pos = atomicAdd(&cursor[d], 1);
  slots[pos] = src[e];
  eids[pos] = e;
  dpos[pos] = d;
}

// ---------------- GCN layer 1 transform: ts1 = dinv * (x @ W1), packed bf16 ----------------
__global__ void k_gcn1(const float4* __restrict__ x4, const float* __restrict__ W1,
                       const float* __restrict__ dinv, unsigned* __restrict__ tout, int N) {
  int t = blockIdx.x * TPB + threadIdx.x;
  int n = t >> 5;
  if (n >= N) return;
  int q = (t & 31) << 2;  // col
  float4 xv = x4[n];
  float s = dinv[n];
  float r[4];
#pragma unroll
  for (int u = 0; u < 4; u++) {
    int j = q + u;
    r[u] = s * (xv.x * W1[j] + xv.y * W1[128 + j] + xv.z * W1[256 + j] + xv.w * W1[384 + j]);
  }
  uint2 p;
  p.x = f2bf_pack(r[0], r[1]);
  p.y = f2bf_pack(r[2], r[3]);
  *(uint2*)&tout[n * 64 + (q >> 1)] = p;
}

// ---------------- CSR aggregate (bf16 in/out, fp32 accum), 4-deep gather pipeline ----------------
template <bool RELU>
__global__ void k_agg(const unsigned* __restrict__ ts, const int* __restrict__ rowoff,
                      const int* __restrict__ deg, const int* __restrict__ slots,
                      const float* __restrict__ dinv, const float* __restrict__ bias,
                      unsigned* __restrict__ hout, int N) {
  int t = blockIdx.x * TPB + threadIdx.x;
  int n = t >> 5;
  if (n >= N) return;
  int q = (t & 31) << 1;  // uint index: covers cols 2q..2q+3
  uint2 sv = *(const uint2*)&ts[n * 64 + q];
  float s0 = bflo(sv.x), s1 = bfhi(sv.x), s2 = bflo(sv.y), s3 = bfhi(sv.y);
  int start = rowoff[n], d = deg[n];
  int j = 0;
  for (; j + 4 <= d; j += 4) {
    int ia = slots[start + j], ib = slots[start + j + 1];
    int ic = slots[start + j + 2], id = slots[start + j + 3];
    uint2 va = *(const uint2*)&ts[(size_t)ia * 64 + q];
    uint2 vb = *(const uint2*)&ts[(size_t)ib * 64 + q];
    uint2 vc = *(const uint2*)&ts[(size_t)ic * 64 + q];
    uint2 vd = *(const uint2*)&ts[(size_t)id * 64 + q];
    s0 += bflo(va.x) + bflo(vb.x) + bflo(vc.x) + bflo(vd.x);
    s1 += bfhi(va.x) + bfhi(vb.x) + bfhi(vc.x) + bfhi(vd.x);
    s2 += bflo(va.y) + bflo(vb.y) + bflo(vc.y) + bflo(vd.y);
    s3 += bfhi(va.y) + bfhi(vb.y) + bfhi(vc.y) + bfhi(vd.y);
  }
  for (; j < d; j++) {
    int s = slots[start + j];
    uint2 v = *(const uint2*)&ts[(size_t)s * 64 + q];
    s0 += bflo(v.x);
    s1 += bfhi(v.x);
    s2 += bflo(v.y);
    s3 += bfhi(v.y);
  }
  float sc = dinv[n];
  int col = q << 1;
  float4 b4 = *(const float4*)&bias[col];
  s0 = s0 * sc + b4.x;
  s1 = s1 * sc + b4.y;
  s2 = s2 * sc + b4.z;
  s3 = s3 * sc + b4.w;
  if (RELU) {
    s0 = fmaxf(s0, 0.f);
    s1 = fmaxf(s1, 0.f);
    s2 = fmaxf(s2, 0.f);
    s3 = fmaxf(s3, 0.f);
  }
  uint2 p;
  p.x = f2bf_pack(s0, s1);
  p.y = f2bf_pack(s2, s3);
  *(uint2*)&hout[n * 64 + q] = p;
}

// ---------------- persistent MFMA GEMM: out = dinv[n] * (A[n]@W), bf16 in/out ----------------
template <bool BIAS, bool DINV>
__global__ __launch_bounds__(256, 2) void k_gemm_bf(const unsigned* __restrict__ A,
                                                    const float* __restrict__ W,
                                                    const float* __restrict__ bias,
                                                    const float* __restrict__ dinv,
                                                    unsigned* __restrict__ out, int N) {
  __shared__ unsigned sA[64 * 64];  // 64 rows x 128 bf16, XOR-swizzled
  __shared__ float sDinv[64];
  int tid = threadIdx.x;
  int wv = tid >> 6, lane = tid & 63;
  int rg = wv >> 1, ch = wv & 1;
  int l31 = lane & 31, h = lane >> 5;

  bf16x8 wf[2][8];
  float bcol[2];
#pragma unroll
  for (int t = 0; t < 2; t++) {
    int col = ch * 64 + 2 * l31 + t;
#pragma unroll
    for (int kk = 0; kk < 8; kk++) {
      int kb = kk * 16 + h * 8;
      bf16x8 v;
#pragma unroll
      for (int u = 0; u < 8; u++) v[u] = f2bf(W[(kb + u) * 128 + col]);
      wf[t][kk] = v;
    }
    bcol[t] = BIAS ? bias[col] : 0.f;
  }

  int ntiles = (N + 63) >> 6;
  for (int tile = blockIdx.x; tile < ntiles; tile += gridDim.x) {
    __syncthreads();
    int row0 = tile << 6;
    for (int idx = tid; idx < 1024; idx += 256) {
      int r = idx >> 4, c4 = idx & 15;
      int n = row0 + r;
      uint4 v = (n < N) ? ((const uint4*)A)[(size_t)n * 16 + c4] : make_uint4(0, 0, 0, 0);
      *(uint4*)&sA[r * 64 + ((c4 * 4) ^ ((r & 15) << 2))] = v;
    }
    if (DINV && tid < 64) sDinv[tid] = (row0 + tid < N) ? dinv[row0 + tid] : 0.f;
    __syncthreads();

    int arow = rg * 32 + l31;
    const char* abase = (const char*)sA + arow * 256;
    int swz = (arow & 15) << 4;
    f32x16 acc[2];
#pragma unroll
    for (int t = 0; t < 2; t++) {
#pragma unroll
      for (int r = 0; r < 16; r++) acc[t][r] = 0.f;
    }
#pragma unroll
    for (int kk = 0; kk < 8; kk++) {
      bf16x8 a = *(const bf16x8*)(abase + ((kk * 32 + h * 16) ^ swz));
      acc[0] = __builtin_amdgcn_mfma_f32_32x32x16_bf16(a, wf[0][kk], acc[0], 0, 0, 0);
      acc[1] = __builtin_amdgcn_mfma_f32_32x32x16_bf16(a, wf[1][kk], acc[1], 0, 0, 0);
    }
#pragma unroll
    for (int r = 0; r < 16; r++) {
      int drow = (r & 3) + 8 * (r >> 2) + 4 * h;
      int n = row0 + rg * 32 + drow;
      if (n < N) {
        float v0 = acc[0][r] + bcol[0];
        float v1 = acc[1][r] + bcol[1];
        if (DINV) {
          float s = sDinv[rg * 32 + drow];
          v0 *= s;
          v1 *= s;
        }
        out[(size_t)n * 64 + ch * 32 + l31] = f2bf_pack(v0, v1);
      }
    }
  }
}

// ---------------- fused dual GEMM: a_s = A@Wm1[0:128]+bm1 ; a_d = A@Wm1[128:256] ----------------
__global__ __launch_bounds__(512, 2) void k_gemm_dual(const unsigned* __restrict__ A,
                                                      const float* __restrict__ Wm1,
                                                      const float* __restrict__ bm1,
                                                      unsigned* __restrict__ out_s,
                                                      unsigned* __restrict__ out_d, int N) {
  __shared__ unsigned sA[64 * 64];
  int tid = threadIdx.x;
  int wv = tid >> 6, lane = tid & 63;
  int part = wv >> 2;  // 0: a_s, 1: a_d
  int w4 = wv & 3;
  int rg = w4 >> 1, ch = w4 & 1;
  int l31 = lane & 31, h = lane >> 5;
  const float* W = Wm1 + (size_t)part * 128 * 128;
  unsigned* outp = part ? out_d : out_s;

  bf16x8 wf[2][8];
  float bcol[2];
#pragma unroll
  for (int t = 0; t < 2; t++) {
    int col = ch * 64 + 2 * l31 + t;
#pragma unroll
    for (int kk = 0; kk < 8; kk++) {
      int kb = kk * 16 + h * 8;
      bf16x8 v;
#pragma unroll
      for (int u = 0; u < 8; u++) v[u] = f2bf(W[(kb + u) * 128 + col]);
      wf[t][kk] = v;
    }
    bcol[t] = part ? 0.f : bm1[col];
  }

  int ntiles = (N + 63) >> 6;
  for (int tile = blockIdx.x; tile < ntiles; tile += gridDim.x) {
    __syncthreads();
    int row0 = tile << 6;
    for (int idx = tid; idx < 1024; idx += 512) {
      int r = idx >> 4, c4 = idx & 15;
      int n = row0 + r;
      uint4 v = (n < N) ? ((const uint4*)A)[(size_t)n * 16 + c4] : make_uint4(0, 0, 0, 0);
      *(uint4*)&sA[r * 64 + ((c4 * 4) ^ ((r & 15) << 2))] = v;
    }
    __syncthreads();

    int arow = rg * 32 + l31;
    const char* abase = (const char*)sA + arow * 256;
    int swz = (arow & 15) << 4;
    f32x16 acc[2];
#pragma unroll
    for (int t = 0; t < 2; t++) {
#pragma unroll
      for (int r = 0; r < 16; r++) acc[t][r] = 0.f;
    }
#pragma unroll
    for (int kk = 0; kk < 8; kk++) {
      bf16x8 a = *(const bf16x8*)(abase + ((kk * 32 + h * 16) ^ swz));
      acc[0] = __builtin_amdgcn_mfma_f32_32x32x16_bf16(a, wf[0][kk], acc[0], 0, 0, 0);
      acc[1] = __builtin_amdgcn_mfma_f32_32x32x16_bf16(a, wf[1][kk], acc[1], 0, 0, 0);
    }
#pragma unroll
    for (int r = 0; r < 16; r++) {
      int drow = (r & 3) + 8 * (r >> 2) + 4 * h;
      int n = row0 + rg * 32 + drow;
      if (n < N) {
        float v0 = acc[0][r] + bcol[0];
        float v1 = acc[1][r] + bcol[1];
        outp[(size_t)n * 64 + ch * 32 + l31] = f2bf_pack(v0, v1);
      }
    }
  }
}

// ---------------- fused edge MLP: dst-sorted + depth-2 cross-tile gather pipeline ----------------
__global__ __launch_bounds__(256, 2) void k_edge_mlp(
    const unsigned* __restrict__ a_s, const unsigned* __restrict__ a_d,
    const float* __restrict__ eattr, const int* __restrict__ slots,
    const int* __restrict__ eids, const int* __restrict__ dpos,
    const float* __restrict__ We, const float* __restrict__ Wm2,
    const float* __restrict__ bm2, const float* __restrict__ Wm3,
    const float* __restrict__ bm3, float* __restrict__ out, int E) {
  __shared__ unsigned sZ1[64 * 64];  // 64 rows x 128 bf16, XOR-swizzled
  __shared__ float sEa[2][64][5];
  __shared__ int sSrc[2][64], sDst[2][64], sEid[2][64];
  __shared__ float sP[64][2];

  int tid = threadIdx.x;
  int wv = tid >> 6;
  int lane = tid & 63;
  int rg = wv >> 1;
  int ch = wv & 1;
  int l31 = lane & 31;
  int h = lane >> 5;

  bf16x8 bfr[2][8];
#pragma unroll
  for (int t = 0; t < 2; t++) {
    int col = ch * 64 + t * 32 + l31;
#pragma unroll
    for (int kk = 0; kk < 8; kk++) {
      int kb = kk * 16 + h * 8;
      bf16x8 v;
#pragma unroll
      for (int u = 0; u < 8; u++) v[u] = f2bf(Wm2[(kb + u) * 128 + col]);
      bfr[t][kk] = v;
    }
  }
  float wm3c[2], bm2c[2];
#pragma unroll
  for (int t = 0; t < 2; t++) {
    int col = ch * 64 + t * 32 + l31;
    wm3c[t] = Wm3[col];
    bm2c[t] = bm2[col];
  }
  float bm3v = bm3[0];
  float2 we[5];
#pragma unroll
  for (int j = 0; j < 5; j++) we[j] = *(const float2*)(We + j * 128 + 2 * lane);

  int ntiles = (E + 63) >> 6;

  // ---- stage(tile, buf) helper, inlined via lambda ----
  auto stage = [&](int t, int b) {
    bool tv = t < ntiles;
    if (tid < 64) {
      int p = (t << 6) + tid;
      bool v = tv && (p < E);
      sSrc[b][tid] = v ? slots[p] : 0;
      sDst[b][tid] = v ? dpos[p] : 0;
      sEid[b][tid] = v ? eids[p] : 0;
    }
    for (int idx = tid; idx < 320; idx += 256) {
      int r = idx / 5, j = idx - r * 5;
      int p = (t << 6) + r;
      bool v = tv && (p < E);
      int e = v ? eids[p] : 0;
      sEa[b][r][j] = v ? eattr[(size_t)e * 5 + j] : 0.f;
    }
  };

  int tile0 = blockIdx.x;
  if (tile0 >= ntiles) return;

  // prologue: stage + gather tile0
  stage(tile0, 0);
  __syncthreads();
  unsigned ua[16], ud[16];
#pragma unroll
  for (int i = 0; i < 16; i++) {
    int r = wv * 16 + i;
    ua[i] = a_s[(size_t)sSrc[0][r] * 64 + lane];
    ud[i] = a_d[(size_t)sDst[0][r] * 64 + lane];
  }

  int c = 0;
  for (int tile = tile0; tile < ntiles; tile += gridDim.x, c ^= 1) {
    // A) stage indices/eattr for the NEXT tile into the other buffer
    stage(tile + gridDim.x, c ^ 1);

    // B) Phase A: compute z1 from prefetched regs -> sZ1
#pragma unroll
    for (int i = 0; i < 16; i++) {
      int r = wv * 16 + i;
      float v0 = bflo(ua[i]) + bflo(ud[i]);
      float v1 = bfhi(ua[i]) + bfhi(ud[i]);
#pragma unroll
      for (int j = 0; j < 5; j++) {
        float ea = sEa[c][r][j];
        v0 = fmaf(ea, we[j].x, v0);
        v1 = fmaf(ea, we[j].y, v1);
      }
      v0 = fmaxf(v0, 0.f);
      v1 = fmaxf(v1, 0.f);
      sZ1[r * 64 + (lane ^ ((r & 15) << 2))] = f2bf_pack(v0, v1);
    }
    __syncthreads();  // sZ1 ready; next-tile indices staged

    // D) issue gathers for next tile (consumed next iteration; latency hidden by Phase B)
    if (tile + gridDim.x < ntiles) {
#pragma unroll
      for (int i = 0; i < 16; i++) {
        int r = wv * 16 + i;
        ua[i] = a_s[(size_t)sSrc[c ^ 1][r] * 64 + lane];
        ud[i] = a_d[(size_t)sDst[c ^ 1][r] * 64 + lane];
      }
    }

    // E) Phase B: C[32 rows][64 cols] via mfma_f32_32x32x16_bf16
    int arow = rg * 32 + l31;
    const char* abase = (const char*)sZ1 + arow * 256;
    int swz = (arow & 15) << 4;
    float p16[16];
#pragma unroll
    for (int r = 0; r < 16; r++) p16[r] = 0.f;
#pragma unroll
    for (int t = 0; t < 2; t++) {
      f32x16 acc;
#pragma unroll
      for (int r = 0; r < 16; r++) acc[r] = 0.f;
#pragma unroll
      for (int kk = 0; kk < 8; kk++) {
        bf16x8 a = *(const bf16x8*)(abase + ((kk * 32 + h * 16) ^ swz));
        acc = __builtin_amdgcn_mfma_f32_32x32x16_bf16(a, bfr[t][kk], acc, 0, 0, 0);
      }
#pragma unroll
      for (int r = 0; r < 16; r++) {
        float z2 = fmaxf(acc[r] + bm2c[t], 0.f);
        p16[r] = fmaf(z2, wm3c[t], p16[r]);
      }
    }
#pragma unroll
    for (int r = 0; r < 16; r++) {
      float p = p16[r];
#pragma unroll
      for (int off = 16; off >= 1; off >>= 1) p += __shfl_xor(p, off, 32);
      if (l31 == 0) {
        int row = (r & 3) + 8 * (r >> 2) + 4 * h;
        sP[rg * 32 + row][ch] = p;
      }
    }
    __syncthreads();  // sP ready

    // G) epilogue: scatter sigmoid to original edge ids
    if (tid < 64) {
      int p = (tile << 6) + tid;
      if (p < E) {
        float pv = sP[tid][0] + sP[tid][1] + bm3v;
        out[sEid[c][tid]] = 1.f / (1.f + __expf(-pv));
      }
    }
    __syncthreads();  // protect sZ1/sP/buf[c] before next iteration overwrites
  }
}

// ---------------- launch ----------------
extern "C" void kernel_launch(void* const* d_in, const int* in_sizes, int n_in,
                              void* d_out, int out_size, void* d_ws, size_t ws_size,
                              hipStream_t stream) {
  const float* x = (const float*)d_in[0];
  const float* eattr = (const float*)d_in[1];
  const float* W1 = (const float*)d_in[2];
  const float* b1 = (const float*)d_in[3];
  const float* W2 = (const float*)d_in[4];
  const float* b2 = (const float*)d_in[5];
  const float* Wm1 = (const float*)d_in[6];
  const float* bm1 = (const float*)d_in[7];
  const float* Wm2 = (const float*)d_in[8];
  const float* bm2 = (const float*)d_in[9];
  const float* Wm3 = (const float*)d_in[10];
  const float* bm3 = (const float*)d_in[11];
  const int* ei = (const int*)d_in[12];
  int N = in_sizes[0] / 4;
  int E = in_sizes[12] / 2;
  const int* src = ei;
  const int* dst = ei + E;
  float* out = (float*)d_out;

  size_t npad = (size_t)((N + 63) & ~63);
  float* dinv = (float*)d_ws;
  unsigned* U1 = (unsigned*)(dinv + npad);
  unsigned* U2 = U1 + (size_t)N * 64;
  unsigned* U3 = U2 + (size_t)N * 64;
  unsigned* U4 = U3 + (size_t)N * 64;
  int* degi = (int*)(U4 + (size_t)N * 64);
  int* rowoff = degi + npad;
  int* cursor = rowoff + npad;
  int* bsum = cursor + npad;  // 256 slots
  int* slots = bsum + 256;
  int* eids = slots + E;
  int* dpos = eids + E;

  int gN = (N + TPB - 1) / TPB;
  int gE = (E + TPB - 1) / TPB;
  int gN32 = (N * 32 + TPB - 1) / TPB;
  int nb1 = (N + SCAN_CHUNK - 1) / SCAN_CHUNK;

  // CSR build (dst-sorted adjacency) + dinv
  k_zero_int<<<gN, TPB, 0, stream>>>(degi, N);
  k_hist<<<gE, TPB, 0, stream>>>(dst, degi, E);
  k_scan_local<<<nb1, SCAN_T, 0, stream>>>(degi, rowoff, bsum, N);
  k_scan_block<<<1, 64, 0, stream>>>(bsum, nb1);
  k_scan_add<<<gN, TPB, 0, stream>>>(rowoff, bsum, cursor, degi, dinv, N);
  k_fill_slots<<<gE, TPB, 0, stream>>>(src, dst, cursor, slots, eids, dpos, E);

  // GCN layer 1: ts1 (U1) -> h1 (U2)
  k_gcn1<<<gN32, TPB, 0, stream>>>((const float4*)x, W1, dinv, U1, N);
  k_agg<true><<<gN32, TPB, 0, stream>>>(U1, rowoff, degi, slots, dinv, b1, U2, N);

  // GCN layer 2: ts2 = dinv*(h1@W2) (U1) -> h2 (U3)
  k_gemm_bf<false, true><<<512, TPB, 0, stream>>>(U2, W2, nullptr, dinv, U1, N);
  k_agg<false><<<gN32, TPB, 0, stream>>>(U1, rowoff, degi, slots, dinv, b2, U3, N);

  // Edge classifier: a_s (U2), a_d (U4) in one fused kernel
  k_gemm_dual<<<512, 512, 0, stream>>>(U3, Wm1, bm1, U2, U4, N);
  k_edge_mlp<<<2048, TPB, 0, stream>>>(U2, U4, eattr, slots, eids, dpos,
                                       Wm1 + 256 * 128, Wm2, bm2, Wm3, bm3, out, E);
}

// Round 8
// 324.244 us; speedup vs baseline: 1.1372x; 1.1372x over previous
//
#include <hip/hip_runtime.h>
#include <math.h>

#define TPB 256
#define SCAN_T 256
#define SCAN_I 4
#define SCAN_CHUNK 1024  // SCAN_T * SCAN_I

typedef __attribute__((ext_vector_type(8))) short bf16x8;
typedef __attribute__((ext_vector_type(16))) float f32x16;

static __device__ __forceinline__ short f2bf(float a) {
  unsigned ua = __builtin_bit_cast(unsigned, a);
  ua = (ua + 0x7fffu + ((ua >> 16) & 1u)) >> 16;
  return (short)ua;
}
static __device__ __forceinline__ unsigned f2bf_pack(float a, float b) {
  unsigned ua = __builtin_bit_cast(unsigned, a);
  unsigned ub = __builtin_bit_cast(unsigned, b);
  ua = (ua + 0x7fffu + ((ua >> 16) & 1u)) >> 16;
  ub = (ub + 0x7fffu + ((ub >> 16) & 1u)) >> 16;
  return ua | (ub << 16);
}
static __device__ __forceinline__ float bflo(unsigned u) {
  return __builtin_bit_cast(float, u << 16);
}
static __device__ __forceinline__ float bfhi(unsigned u) {
  return __builtin_bit_cast(float, u & 0xffff0000u);
}

// ---------------- CSR build ----------------
__global__ void k_zero_int(int* __restrict__ p, int n) {
  int t = blockIdx.x * TPB + threadIdx.x;
  if (t < n) p[t] = 0;
}

__global__ void k_hist(const int* __restrict__ dst, int* __restrict__ deg, int E) {
  int t = blockIdx.x * TPB + threadIdx.x;
  if (t < E) atomicAdd(&deg[dst[t]], 1);
}

// per-block exclusive scan of deg -> loc, block sums -> bsum; also dinv = rsqrt(deg+1)
__global__ __launch_bounds__(SCAN_T) void k_scan_local(const int* __restrict__ deg,
                                                       int* __restrict__ loc,
                                                       int* __restrict__ bsum,
                                                       float* __restrict__ dinv, int N) {
  __shared__ int s[SCAN_T];
  int b = blockIdx.x, t = threadIdx.x;
  int base = b * SCAN_CHUNK + t * SCAN_I;
  int v[SCAN_I];
  int sum = 0;
#pragma unroll
  for (int u = 0; u < SCAN_I; u++) {
    int x = (base + u < N) ? deg[base + u] : 0;
    if (base + u < N) dinv[base + u] = rsqrtf((float)x + 1.0f);
    v[u] = sum;
    sum += x;
  }
  s[t] = sum;
  __syncthreads();
#pragma unroll
  for (int off = 1; off < SCAN_T; off <<= 1) {
    int x = (t >= off) ? s[t - off] : 0;
    __syncthreads();
    s[t] += x;
    __syncthreads();
  }
  int excl = (t == 0) ? 0 : s[t - 1];
#pragma unroll
  for (int u = 0; u < SCAN_I; u++)
    if (base + u < N) loc[base + u] = v[u] + excl;
  if (t == SCAN_T - 1) bsum[b] = s[t];
}

// parallel exclusive scan of bsum (nb <= 128) with one wave
__global__ void k_scan_block(int* __restrict__ bsum, int nb) {
  int t = threadIdx.x;  // 0..63
  int i0 = 2 * t, i1 = 2 * t + 1;
  int a = (i0 < nb) ? bsum[i0] : 0;
  int b = (i1 < nb) ? bsum[i1] : 0;
  int s = a + b;
#pragma unroll
  for (int off = 1; off < 64; off <<= 1) {
    int u = __shfl_up(s, off, 64);
    if (t >= off) s += u;
  }
  int excl = s - (a + b);  // exclusive prefix of this pair
  if (i0 < nb) bsum[i0] = excl;
  if (i1 < nb) bsum[i1] = excl + a;
}

__global__ void k_scan_add(int* __restrict__ rowoff, const int* __restrict__ bsum,
                           int* __restrict__ cursor, int N) {
  int t = blockIdx.x * TPB + threadIdx.x;
  if (t >= N) return;
  int ro = rowoff[t] + bsum[t / SCAN_CHUNK];
  rowoff[t] = ro;
  cursor[t] = ro;
}

// slots[pos]=src, eids[pos]=edge id, dpos[pos]=dst  (dst-sorted position order)
__global__ void k_fill_slots(const int* __restrict__ src, const int* __restrict__ dst,
                             int* __restrict__ cursor, int* __restrict__ slots,
                             int* __restrict__ eids, int* __restrict__ dpos, int E) {
  int e = blockIdx.x * TPB + threadIdx.x;
  if (e >= E) return;
  int d = dst[e];
  int pos = atomicAdd(&cursor[d], 1);
  slots[pos] = src[e];
  eids[pos] = e;
  dpos[pos] = d;
}

// ---------------- GCN layer 1 transform: ts1 = dinv * (x @ W1), packed bf16 ----------------
__global__ void k_gcn1(const float4* __restrict__ x4, const float* __restrict__ W1,
                       const float* __restrict__ dinv, unsigned* __restrict__ tout, int N) {
  int t = blockIdx.x * TPB + threadIdx.x;
  int n = t >> 5;
  if (n >= N) return;
  int q = (t & 31) << 2;  // col
  float4 xv = x4[n];
  float s = dinv[n];
  float r[4];
#pragma unroll
  for (int u = 0; u < 4; u++) {
    int j = q + u;
    r[u] = s * (xv.x * W1[j] + xv.y * W1[128 + j] + xv.z * W1[256 + j] + xv.w * W1[384 + j]);
  }
  uint2 p;
  p.x = f2bf_pack(r[0], r[1]);
  p.y = f2bf_pack(r[2], r[3]);
  *(uint2*)&tout[n * 64 + (q >> 1)] = p;
}

// ---------------- CSR aggregate (bf16 in/out, fp32 accum), 8-deep gather pipeline ----------------
template <bool RELU>
__global__ void k_agg(const unsigned* __restrict__ ts, const int* __restrict__ rowoff,
                      const int* __restrict__ deg, const int* __restrict__ slots,
                      const float* __restrict__ dinv, const float* __restrict__ bias,
                      unsigned* __restrict__ hout, int N) {
  int t = blockIdx.x * TPB + threadIdx.x;
  int n = t >> 5;
  if (n >= N) return;
  int q = (t & 31) << 1;  // uint index: covers cols 2q..2q+3
  uint2 sv = *(const uint2*)&ts[n * 64 + q];
  float s0 = bflo(sv.x), s1 = bfhi(sv.x), s2 = bflo(sv.y), s3 = bfhi(sv.y);
  int start = rowoff[n], d = deg[n];
  int j = 0;
  for (; j + 8 <= d; j += 8) {
    int sl[8];
#pragma unroll
    for (int u = 0; u < 8; u++) sl[u] = slots[start + j + u];
    uint2 v[8];
#pragma unroll
    for (int u = 0; u < 8; u++) v[u] = *(const uint2*)&ts[(size_t)sl[u] * 64 + q];
#pragma unroll
    for (int u = 0; u < 8; u++) {
      s0 += bflo(v[u].x);
      s1 += bfhi(v[u].x);
      s2 += bflo(v[u].y);
      s3 += bfhi(v[u].y);
    }
  }
  if (j + 4 <= d) {
    int sl[4];
#pragma unroll
    for (int u = 0; u < 4; u++) sl[u] = slots[start + j + u];
    uint2 v[4];
#pragma unroll
    for (int u = 0; u < 4; u++) v[u] = *(const uint2*)&ts[(size_t)sl[u] * 64 + q];
#pragma unroll
    for (int u = 0; u < 4; u++) {
      s0 += bflo(v[u].x);
      s1 += bfhi(v[u].x);
      s2 += bflo(v[u].y);
      s3 += bfhi(v[u].y);
    }
    j += 4;
  }
  for (; j < d; j++) {
    int s = slots[start + j];
    uint2 v = *(const uint2*)&ts[(size_t)s * 64 + q];
    s0 += bflo(v.x);
    s1 += bfhi(v.x);
    s2 += bflo(v.y);
    s3 += bfhi(v.y);
  }
  float sc = dinv[n];
  int col = q << 1;
  float4 b4 = *(const float4*)&bias[col];
  s0 = s0 * sc + b4.x;
  s1 = s1 * sc + b4.y;
  s2 = s2 * sc + b4.z;
  s3 = s3 * sc + b4.w;
  if (RELU) {
    s0 = fmaxf(s0, 0.f);
    s1 = fmaxf(s1, 0.f);
    s2 = fmaxf(s2, 0.f);
    s3 = fmaxf(s3, 0.f);
  }
  uint2 p;
  p.x = f2bf_pack(s0, s1);
  p.y = f2bf_pack(s2, s3);
  *(uint2*)&hout[n * 64 + q] = p;
}

// ---------------- persistent MFMA GEMM: out = dinv[n] * (A[n]@W), bf16 in/out ----------------
template <bool BIAS, bool DINV>
__global__ __launch_bounds__(256, 2) void k_gemm_bf(const unsigned* __restrict__ A,
                                                    const float* __restrict__ W,
                                                    const float* __restrict__ bias,
                                                    const float* __restrict__ dinv,
                                                    unsigned* __restrict__ out, int N) {
  __shared__ unsigned sA[64 * 64];  // 64 rows x 128 bf16, XOR-swizzled
  __shared__ float sDinv[64];
  int tid = threadIdx.x;
  int wv = tid >> 6, lane = tid & 63;
  int rg = wv >> 1, ch = wv & 1;
  int l31 = lane & 31, h = lane >> 5;

  bf16x8 wf[2][8];
  float bcol[2];
#pragma unroll
  for (int t = 0; t < 2; t++) {
    int col = ch * 64 + 2 * l31 + t;
#pragma unroll
    for (int kk = 0; kk < 8; kk++) {
      int kb = kk * 16 + h * 8;
      bf16x8 v;
#pragma unroll
      for (int u = 0; u < 8; u++) v[u] = f2bf(W[(kb + u) * 128 + col]);
      wf[t][kk] = v;
    }
    bcol[t] = BIAS ? bias[col] : 0.f;
  }

  int ntiles = (N + 63) >> 6;
  for (int tile = blockIdx.x; tile < ntiles; tile += gridDim.x) {
    __syncthreads();
    int row0 = tile << 6;
    for (int idx = tid; idx < 1024; idx += 256) {
      int r = idx >> 4, c4 = idx & 15;
      int n = row0 + r;
      uint4 v = (n < N) ? ((const uint4*)A)[(size_t)n * 16 + c4] : make_uint4(0, 0, 0, 0);
      *(uint4*)&sA[r * 64 + ((c4 * 4) ^ ((r & 15) << 2))] = v;
    }
    if (DINV && tid < 64) sDinv[tid] = (row0 + tid < N) ? dinv[row0 + tid] : 0.f;
    __syncthreads();

    int arow = rg * 32 + l31;
    const char* abase = (const char*)sA + arow * 256;
    int swz = (arow & 15) << 4;
    f32x16 acc[2];
#pragma unroll
    for (int t = 0; t < 2; t++) {
#pragma unroll
      for (int r = 0; r < 16; r++) acc[t][r] = 0.f;
    }
#pragma unroll
    for (int kk = 0; kk < 8; kk++) {
      bf16x8 a = *(const bf16x8*)(abase + ((kk * 32 + h * 16) ^ swz));
      acc[0] = __builtin_amdgcn_mfma_f32_32x32x16_bf16(a, wf[0][kk], acc[0], 0, 0, 0);
      acc[1] = __builtin_amdgcn_mfma_f32_32x32x16_bf16(a, wf[1][kk], acc[1], 0, 0, 0);
    }
#pragma unroll
    for (int r = 0; r < 16; r++) {
      int drow = (r & 3) + 8 * (r >> 2) + 4 * h;
      int n = row0 + rg * 32 + drow;
      if (n < N) {
        float v0 = acc[0][r] + bcol[0];
        float v1 = acc[1][r] + bcol[1];
        if (DINV) {
          float s = sDinv[rg * 32 + drow];
          v0 *= s;
          v1 *= s;
        }
        out[(size_t)n * 64 + ch * 32 + l31] = f2bf_pack(v0, v1);
      }
    }
  }
}

// ---------------- fused dual GEMM: a_s = A@Wm1[0:128]+bm1 ; a_d = A@Wm1[128:256] ----------------
__global__ __launch_bounds__(512, 2) void k_gemm_dual(const unsigned* __restrict__ A,
                                                      const float* __restrict__ Wm1,
                                                      const float* __restrict__ bm1,
                                                      unsigned* __restrict__ out_s,
                                                      unsigned* __restrict__ out_d, int N) {
  __shared__ unsigned sA[64 * 64];
  int tid = threadIdx.x;
  int wv = tid >> 6, lane = tid & 63;
  int part = wv >> 2;  // 0: a_s, 1: a_d
  int w4 = wv & 3;
  int rg = w4 >> 1, ch = w4 & 1;
  int l31 = lane & 31, h = lane >> 5;
  const float* W = Wm1 + (size_t)part * 128 * 128;
  unsigned* outp = part ? out_d : out_s;

  bf16x8 wf[2][8];
  float bcol[2];
#pragma unroll
  for (int t = 0; t < 2; t++) {
    int col = ch * 64 + 2 * l31 + t;
#pragma unroll
    for (int kk = 0; kk < 8; kk++) {
      int kb = kk * 16 + h * 8;
      bf16x8 v;
#pragma unroll
      for (int u = 0; u < 8; u++) v[u] = f2bf(W[(kb + u) * 128 + col]);
      wf[t][kk] = v;
    }
    bcol[t] = part ? 0.f : bm1[col];
  }

  int ntiles = (N + 63) >> 6;
  for (int tile = blockIdx.x; tile < ntiles; tile += gridDim.x) {
    __syncthreads();
    int row0 = tile << 6;
    for (int idx = tid; idx < 1024; idx += 512) {
      int r = idx >> 4, c4 = idx & 15;
      int n = row0 + r;
      uint4 v = (n < N) ? ((const uint4*)A)[(size_t)n * 16 + c4] : make_uint4(0, 0, 0, 0);
      *(uint4*)&sA[r * 64 + ((c4 * 4) ^ ((r & 15) << 2))] = v;
    }
    __syncthreads();

    int arow = rg * 32 + l31;
    const char* abase = (const char*)sA + arow * 256;
    int swz = (arow & 15) << 4;
    f32x16 acc[2];
#pragma unroll
    for (int t = 0; t < 2; t++) {
#pragma unroll
      for (int r = 0; r < 16; r++) acc[t][r] = 0.f;
    }
#pragma unroll
    for (int kk = 0; kk < 8; kk++) {
      bf16x8 a = *(const bf16x8*)(abase + ((kk * 32 + h * 16) ^ swz));
      acc[0] = __builtin_amdgcn_mfma_f32_32x32x16_bf16(a, wf[0][kk], acc[0], 0, 0, 0);
      acc[1] = __builtin_amdgcn_mfma_f32_32x32x16_bf16(a, wf[1][kk], acc[1], 0, 0, 0);
    }
#pragma unroll
    for (int r = 0; r < 16; r++) {
      int drow = (r & 3) + 8 * (r >> 2) + 4 * h;
      int n = row0 + rg * 32 + drow;
      if (n < N) {
        float v0 = acc[0][r] + bcol[0];
        float v1 = acc[1][r] + bcol[1];
        outp[(size_t)n * 64 + ch * 32 + l31] = f2bf_pack(v0, v1);
      }
    }
  }
}

// ---------------- fused edge MLP: dst-sorted order + full gather prefetch, 3 waves/EU ----------------
__global__ __launch_bounds__(256, 3) void k_edge_mlp(
    const unsigned* __restrict__ a_s, const unsigned* __restrict__ a_d,
    const float* __restrict__ eattr, const int* __restrict__ slots,
    const int* __restrict__ eids, const int* __restrict__ dpos,
    const float* __restrict__ We, const float* __restrict__ Wm2,
    const float* __restrict__ bm2, const float* __restrict__ Wm3,
    const float* __restrict__ bm3, float* __restrict__ out, int E) {
  __shared__ unsigned sZ1[64 * 64];  // 64 rows x 128 bf16, XOR-swizzled
  __shared__ float sEa[64][5];
  __shared__ int sSrc[64], sDst[64], sEid[64];
  __shared__ float sP[64][2];

  int tid = threadIdx.x;
  int wv = tid >> 6;
  int lane = tid & 63;
  int rg = wv >> 1;
  int ch = wv & 1;
  int l31 = lane & 31;
  int h = lane >> 5;

  bf16x8 bfr[2][8];
#pragma unroll
  for (int t = 0; t < 2; t++) {
    int col = ch * 64 + t * 32 + l31;
#pragma unroll
    for (int kk = 0; kk < 8; kk++) {
      int kb = kk * 16 + h * 8;
      bf16x8 v;
#pragma unroll
      for (int u = 0; u < 8; u++) v[u] = f2bf(Wm2[(kb + u) * 128 + col]);
      bfr[t][kk] = v;
    }
  }
  float wm3c[2], bm2c[2];
#pragma unroll
  for (int t = 0; t < 2; t++) {
    int col = ch * 64 + t * 32 + l31;
    wm3c[t] = Wm3[col];
    bm2c[t] = bm2[col];
  }
  float bm3v = bm3[0];
  float2 we[5];
#pragma unroll
  for (int j = 0; j < 5; j++) we[j] = *(const float2*)(We + j * 128 + 2 * lane);

  int ntiles = (E + 63) >> 6;
  for (int tile = blockIdx.x; tile < ntiles; tile += gridDim.x) {
    __syncthreads();
    int p0 = tile << 6;
    if (tid < 64) {
      int p = p0 + tid;
      sSrc[tid] = (p < E) ? slots[p] : 0;
      sDst[tid] = (p < E) ? dpos[p] : 0;
      sEid[tid] = (p < E) ? eids[p] : 0;
    }
    for (int idx = tid; idx < 320; idx += 256) {
      int r = idx / 5, j = idx - r * 5;
      int p = p0 + r;
      int e = (p < E) ? eids[p] : 0;
      sEa[r][j] = (p < E) ? eattr[(size_t)e * 5 + j] : 0.f;
    }
    __syncthreads();

    // Phase A: issue ALL 32 gathers first (static-indexed regs), then compute
    unsigned ua[16], ud[16];
#pragma unroll
    for (int i = 0; i < 16; i++) {
      int r = wv * 16 + i;
      ua[i] = a_s[(size_t)sSrc[r] * 64 + lane];
      ud[i] = a_d[(size_t)sDst[r] * 64 + lane];
    }
#pragma unroll
    for (int i = 0; i < 16; i++) {
      int r = wv * 16 + i;
      float v0 = bflo(ua[i]) + bflo(ud[i]);
      float v1 = bfhi(ua[i]) + bfhi(ud[i]);
#pragma unroll
      for (int j = 0; j < 5; j++) {
        float ea = sEa[r][j];
        v0 = fmaf(ea, we[j].x, v0);
        v1 = fmaf(ea, we[j].y, v1);
      }
      v0 = fmaxf(v0, 0.f);
      v1 = fmaxf(v1, 0.f);
      sZ1[r * 64 + (lane ^ ((r & 15) << 2))] = f2bf_pack(v0, v1);
    }
    __syncthreads();

    // Phase B: C[32 rows][64 cols] via mfma_f32_32x32x16_bf16
    int arow = rg * 32 + l31;
    const char* abase = (const char*)sZ1 + arow * 256;
    int swz = (arow & 15) << 4;
    float p16[16];
#pragma unroll
    for (int r = 0; r < 16; r++) p16[r] = 0.f;
#pragma unroll
    for (int t = 0; t < 2; t++) {
      f32x16 acc;
#pragma unroll
      for (int r = 0; r < 16; r++) acc[r] = 0.f;
#pragma unroll
      for (int kk = 0; kk < 8; kk++) {
        bf16x8 a = *(const bf16x8*)(abase + ((kk * 32 + h * 16) ^ swz));
        acc = __builtin_amdgcn_mfma_f32_32x32x16_bf16(a, bfr[t][kk], acc, 0, 0, 0);
      }
#pragma unroll
      for (int r = 0; r < 16; r++) {
        float z2 = fmaxf(acc[r] + bm2c[t], 0.f);
        p16[r] = fmaf(z2, wm3c[t], p16[r]);
      }
    }
#pragma unroll
    for (int r = 0; r < 16; r++) {
      float p = p16[r];
#pragma unroll
      for (int off = 16; off >= 1; off >>= 1) p += __shfl_xor(p, off, 32);
      if (l31 == 0) {
        int row = (r & 3) + 8 * (r >> 2) + 4 * h;
        sP[rg * 32 + row][ch] = p;
      }
    }
    __syncthreads();
    if (tid < 64) {
      int p = p0 + tid;
      if (p < E) {
        float pv = sP[tid][0] + sP[tid][1] + bm3v;
        out[sEid[tid]] = 1.f / (1.f + __expf(-pv));
      }
    }
  }
}

// ---------------- launch ----------------
extern "C" void kernel_launch(void* const* d_in, const int* in_sizes, int n_in,
                              void* d_out, int out_size, void* d_ws, size_t ws_size,
                              hipStream_t stream) {
  const float* x = (const float*)d_in[0];
  const float* eattr = (const float*)d_in[1];
  const float* W1 = (const float*)d_in[2];
  const float* b1 = (const float*)d_in[3];
  const float* W2 = (const float*)d_in[4];
  const float* b2 = (const float*)d_in[5];
  const float* Wm1 = (const float*)d_in[6];
  const float* bm1 = (const float*)d_in[7];
  const float* Wm2 = (const float*)d_in[8];
  const float* bm2 = (const float*)d_in[9];
  const float* Wm3 = (const float*)d_in[10];
  const float* bm3 = (const float*)d_in[11];
  const int* ei = (const int*)d_in[12];
  int N = in_sizes[0] / 4;
  int E = in_sizes[12] / 2;
  const int* src = ei;
  const int* dst = ei + E;
  float* out = (float*)d_out;

  size_t npad = (size_t)((N + 63) & ~63);
  float* dinv = (float*)d_ws;
  unsigned* U1 = (unsigned*)(dinv + npad);
  unsigned* U2 = U1 + (size_t)N * 64;
  unsigned* U3 = U2 + (size_t)N * 64;
  unsigned* U4 = U3 + (size_t)N * 64;
  int* degi = (int*)(U4 + (size_t)N * 64);
  int* rowoff = degi + npad;
  int* cursor = rowoff + npad;
  int* bsum = cursor + npad;  // 256 slots
  int* slots = bsum + 256;
  int* eids = slots + E;
  int* dpos = eids + E;

  int gN = (N + TPB - 1) / TPB;
  int gE = (E + TPB - 1) / TPB;
  int gN32 = (N * 32 + TPB - 1) / TPB;
  int nb1 = (N + SCAN_CHUNK - 1) / SCAN_CHUNK;

  // CSR build (dst-sorted adjacency) + dinv
  k_zero_int<<<gN, TPB, 0, stream>>>(degi, N);
  k_hist<<<gE, TPB, 0, stream>>>(dst, degi, E);
  k_scan_local<<<nb1, SCAN_T, 0, stream>>>(degi, rowoff, bsum, dinv, N);
  k_scan_block<<<1, 64, 0, stream>>>(bsum, nb1);
  k_scan_add<<<gN, TPB, 0, stream>>>(rowoff, bsum, cursor, N);
  k_fill_slots<<<gE, TPB, 0, stream>>>(src, dst, cursor, slots, eids, dpos, E);

  // GCN layer 1: ts1 (U1) -> h1 (U2)
  k_gcn1<<<gN32, TPB, 0, stream>>>((const float4*)x, W1, dinv, U1, N);
  k_agg<true><<<gN32, TPB, 0, stream>>>(U1, rowoff, degi, slots, dinv, b1, U2, N);

  // GCN layer 2: ts2 = dinv*(h1@W2) (U1) -> h2 (U3)
  k_gemm_bf<false, true><<<512, TPB, 0, stream>>>(U2, W2, nullptr, dinv, U1, N);
  k_agg<false><<<gN32, TPB, 0, stream>>>(U1, rowoff, degi, slots, dinv, b2, U3, N);

  // Edge classifier: a_s (U2), a_d (U4) in one fused kernel
  k_gemm_dual<<<512, 512, 0, stream>>>(U3, Wm1, bm1, U2, U4, N);
  k_edge_mlp<<<2048, TPB, 0, stream>>>(U2, U4, eattr, slots, eids, dpos,
                                       Wm1 + 256 * 128, Wm2, bm2, Wm3, bm3, out, E);
}